// Round 13
// baseline (256.148 us; speedup 1.0000x reference)
//
#include <hip/hip_runtime.h>
#include <cmath>
#include <cstdint>

static constexpr int kB = 32;
static constexpr int kL = 512;
static constexpr int kD = 1024;
static constexpr int kNT = kB * kL;      // total tokens
#define NEGF (-9.0e15f)
#define SCALE 0.03125f                   // 1/sqrt(1024)

typedef __bf16 bf16x8 __attribute__((ext_vector_type(8)));
typedef __bf16 bf16x4 __attribute__((ext_vector_type(4)));
typedef float f32x4 __attribute__((ext_vector_type(4)));

// ---------------- helpers ----------------
__device__ __forceinline__ float wave_sum(float v){
#pragma unroll
  for(int o=32;o>0;o>>=1) v += __shfl_xor(v,o,64);
  return v;
}
__device__ __forceinline__ float wave_max(float v){
#pragma unroll
  for(int o=32;o>0;o>>=1) v = fmaxf(v,__shfl_xor(v,o,64));
  return v;
}
template<int NW>
__device__ __forceinline__ float blk_sum(float v, float* red){
  v = wave_sum(v);
  __syncthreads();
  if((threadIdx.x&63)==0) red[threadIdx.x>>6]=v;
  __syncthreads();
  float r = red[0];
#pragma unroll
  for(int i=1;i<NW;i++) r += red[i];
  return r;
}
template<int NW>
__device__ __forceinline__ float blk_max(float v, float* red){
  v = wave_max(v);
  __syncthreads();
  if((threadIdx.x&63)==0) red[threadIdx.x>>6]=v;
  __syncthreads();
  float r = red[0];
#pragma unroll
  for(int i=1;i<NW;i++) r = fmaxf(r, red[i]);
  return r;
}

__device__ __forceinline__ void gload16(const void* g, void* l){
  __builtin_amdgcn_global_load_lds(
      (const __attribute__((address_space(1))) void*)g,
      (__attribute__((address_space(3))) void*)l, 16, 0, 0);
}

__device__ __forceinline__ float fast_tanh(float x){
  return 1.f - 2.f / (__expf(2.f * x) + 1.f);
}

// bijective XCD swizzle (m204)
__device__ __forceinline__ void xcd_remap(int gx, int gy, int gz, int& ox, int& oy, int& oz){
  int flat = blockIdx.x + gx*(blockIdx.y + gy*blockIdx.z);
  int nwg = gx*gy*gz;
  int c = flat & 7, j = flat >> 3;
  int logical = c*(nwg >> 3) + j;
  ox = logical % gx; int rest = logical / gx;
  oy = rest % gy; oz = rest / gy;
}

// ---------------- masks / sep_pos / stripe counts / c init ----------------
__global__ __launch_bounds__(256) void masks_kernel(
    const int* __restrict__ ids, const int* __restrict__ pad_p, const int* __restrict__ sep_p,
    int* __restrict__ n_fm, int* __restrict__ n_om,
    int* __restrict__ nfs, int* __restrict__ nos,
    unsigned char* __restrict__ fm, unsigned char* __restrict__ om,
    float* __restrict__ c_sup, float* __restrict__ c_rep)
{
  int b = blockIdx.x, t = threadIdx.x;
  int pad = pad_p[0], sep = sep_p[0];
  __shared__ int s_first, s_vl, s_nf, s_no, s_sp;
  __shared__ int s_nfs[4], s_nos[4];
  if (t == 0){ s_first = kL; s_vl = 0; s_nf = 0; s_no = 0; }
  if (t < 4){ s_nfs[t] = 0; s_nos[t] = 0; }
  __syncthreads();
  int id0 = ids[b*kL + t], id1 = ids[b*kL + t + 256];
  int v0 = (id0 != pad) ? 1 : 0, v1 = (id1 != pad) ? 1 : 0;
  int fl = kL;
  if (id0 == sep) fl = t;
  if (id1 == sep && (t + 256) < fl) fl = t + 256;
  atomicMin(&s_first, fl);
  atomicAdd(&s_vl, v0 + v1);
  __syncthreads();
  if (t == 0){
    int vl = s_vl;
    int fb = vl / 2; if (fb < 1) fb = 1; if (fb > kL - 2) fb = kL - 2;
    s_sp = (s_first < kL) ? s_first : fb;
  }
  __syncthreads();
  int sp = s_sp;
  int f0 = ((t < sp) && v0) ? 1 : 0,         o0 = ((t > sp) && v0) ? 1 : 0;
  int f1 = (((t+256) < sp) && v1) ? 1 : 0,   o1 = (((t+256) > sp) && v1) ? 1 : 0;
  fm[b*kL+t] = (unsigned char)f0; fm[b*kL+t+256] = (unsigned char)f1;
  om[b*kL+t] = (unsigned char)o0; om[b*kL+t+256] = (unsigned char)o1;
  atomicAdd(&s_nf, f0 + f1); atomicAdd(&s_no, o0 + o1);
  if (f0) atomicAdd(&s_nfs[t>>7], 1);
  if (o0) atomicAdd(&s_nos[t>>7], 1);
  if (f1) atomicAdd(&s_nfs[(t+256)>>7], 1);
  if (o1) atomicAdd(&s_nos[(t+256)>>7], 1);
  __syncthreads();
  if (t == 0){ n_fm[b] = s_nf; n_om[b] = s_no; }
  if (t < 4){ nfs[b*4 + t] = s_nfs[t]; nos[b*4 + t] = s_nos[t]; }
  float u = (s_no == 0 && s_nf > 0) ? (1.0f/(float)kL) : 0.0f;
  c_sup[b*kL+t] = u; c_sup[b*kL+t+256] = u;
  c_rep[b*kL+t] = u; c_rep[b*kL+t+256] = u;
}

// ---------------- W f32 -> bf16 (6 mats) ----------------
__global__ __launch_bounds__(256) void conv_w_kernel(
    const float* w0, const float* w1, const float* w2,
    const float* w3, const float* w4, const float* w5, __bf16* __restrict__ Wb)
{
  const float* W;
  switch (blockIdx.y){
    case 0: W = w0; break; case 1: W = w1; break; case 2: W = w2; break;
    case 3: W = w3; break; case 4: W = w4; break; default: W = w5; break;
  }
  size_t i = ((size_t)blockIdx.x * 256 + threadIdx.x) * 8;
  float4 a = *reinterpret_cast<const float4*>(W + i);
  float4 b = *reinterpret_cast<const float4*>(W + i + 4);
  bf16x8 v;
  v[0]=(__bf16)a.x; v[1]=(__bf16)a.y; v[2]=(__bf16)a.z; v[3]=(__bf16)a.w;
  v[4]=(__bf16)b.x; v[5]=(__bf16)b.y; v[6]=(__bf16)b.z; v[7]=(__bf16)b.w;
  *reinterpret_cast<bf16x8*>(Wb + (size_t)blockIdx.y * kD * kD + i) = v;
}

// ---------------- bias vectors: vecs4[m]=M_m@v_m (m<4), m==4: scon = bcq.bck ----------------
__global__ __launch_bounds__(256) void wb_vec_kernel(
    const float* wsk, const float* bsq, const float* wrk, const float* brq,
    const float* wck, const float* bcq, const float* wcq, const float* bck,
    float* __restrict__ vecs4, float* __restrict__ scon_s)
{
  int m = blockIdx.y;
  int lane = threadIdx.x & 63;
  if (m == 4){
    if (blockIdx.x != 0 || threadIdx.x >= 64) return;
    float acc = 0.f;
    for (int i = lane; i < kD; i += 64) acc += bcq[i]*bck[i];
    acc = wave_sum(acc);
    if (lane == 0) scon_s[0] = acc;
    return;
  }
  const float* M; const float* v;
  switch(m){
    case 0: M=wsk; v=bsq; break; case 1: M=wrk; v=brq; break;
    case 2: M=wck; v=bcq; break; default: M=wcq; v=bck; break;
  }
  int e = blockIdx.x*4 + (threadIdx.x>>6);
  const float4* Mr = reinterpret_cast<const float4*>(M + (size_t)e*kD);
  const float4* vr = reinterpret_cast<const float4*>(v);
  float acc = 0.f;
#pragma unroll 4
  for (int i = lane; i < kD/4; i += 64){
    float4 a = Mr[i], w = vr[i];
    acc += a.x*w.x + a.y*w.y + a.z*w.z + a.w*w.w;
  }
  acc = wave_sum(acc);
  if (lane == 0) vecs4[m*kD + e] = acc;
}

// ---------------- fused: x->bf16 + anomaly logits + 4 per-token dots ----------------
__global__ __launch_bounds__(256) void prep_x_kernel(
    const float* __restrict__ x, const float* __restrict__ w_anom, const float* __restrict__ b_anom,
    const float* __restrict__ vecs4, __bf16* __restrict__ xb,
    float* __restrict__ logits, float* __restrict__ tokc)
{
  int w = threadIdx.x >> 6;
  int row = blockIdx.x*2 + (threadIdx.x>>7);
  int li = threadIdx.x & 127;
  size_t base = (size_t)row*kD + li*8;
  float4 a = *reinterpret_cast<const float4*>(x + base);
  float4 b4 = *reinterpret_cast<const float4*>(x + base + 4);
  bf16x8 v;
  v[0]=(__bf16)a.x; v[1]=(__bf16)a.y; v[2]=(__bf16)a.z; v[3]=(__bf16)a.w;
  v[4]=(__bf16)b4.x; v[5]=(__bf16)b4.y; v[6]=(__bf16)b4.z; v[7]=(__bf16)b4.w;
  *reinterpret_cast<bf16x8*>(xb + base) = v;

  const float* vp[5] = {w_anom, vecs4, vecs4+kD, vecs4+2*kD, vecs4+3*kD};
  float d[5];
#pragma unroll
  for (int j = 0; j < 5; j++){
    float4 wa = *reinterpret_cast<const float4*>(vp[j] + li*8);
    float4 wb2 = *reinterpret_cast<const float4*>(vp[j] + li*8 + 4);
    d[j] = a.x*wa.x + a.y*wa.y + a.z*wa.z + a.w*wa.w
         + b4.x*wb2.x + b4.y*wb2.y + b4.z*wb2.z + b4.w*wb2.w;
    d[j] = wave_sum(d[j]);
  }
  __shared__ float red[4][5];
  if ((threadIdx.x & 63) == 0){
#pragma unroll
    for (int j = 0; j < 5; j++) red[w][j] = d[j];
  }
  __syncthreads();
  if ((threadIdx.x & 127) == 0){
    int w0 = (threadIdx.x >> 7) * 2;
    logits[row] = red[w0][0] + red[w0+1][0] + b_anom[0];
#pragma unroll
    for (int j = 1; j < 5; j++)
      tokc[(j-1)*kNT + row] = red[w0][j] + red[w0+1][j];
  }
}

// ---------------- gate softmax ----------------
__global__ __launch_bounds__(256) void gate_kernel(const float* __restrict__ logits,
    const unsigned char* __restrict__ fm, const int* __restrict__ n_fm, float* __restrict__ gate)
{
  int b = blockIdx.x, t = threadIdx.x;
  __shared__ float red[4];
  if (n_fm[b] == 0){ gate[b*kL+t] = 0.f; gate[b*kL+t+256] = 0.f; return; }
  int f0 = fm[b*kL+t], f1 = fm[b*kL+t+256];
  float l0 = f0 ? logits[b*kL+t]     : -INFINITY;
  float l1 = f1 ? logits[b*kL+t+256] : -INFINITY;
  float m = blk_max<4>(fmaxf(l0, l1), red);
  float e0 = f0 ? __expf(l0 - m) : 0.f;
  float e1 = f1 ? __expf(l1 - m) : 0.f;
  float Z = blk_sum<4>(e0 + e1, red);
  gate[b*kL+t]     = e0 / Z;
  gate[b*kL+t+256] = e1 / Z;
}

// ---------------- 128x64 NT GEMM core (3-buffer counted-vmcnt pipeline) ----------------
// Same PROVEN R4-R9 sync template (stage(t+2); vmcnt(N) BEFORE barrier;
// compute; barrier), tile narrowed to 128x64: 12KB/buffer -> 36KB LDS
// -> 4 blocks/CU (vs 3), doubling active grid for TLP drain-hiding.
// 3 loads/stage -> steady-state 9 outstanding, vmcnt(6) certifies tile t.
__device__ __forceinline__ void gemm_core_n64(
    const __bf16* __restrict__ A, const __bf16* __restrict__ B,
    int m0, int n0, f32x4 (&acc)[4][2], __bf16* smem)
{
  const int tid = threadIdx.x, lane = tid & 63, wid = tid >> 6;
  const int wm = wid * 32;                               // wave owns 32 rows x 64 cols
  const int r2 = tid >> 2, sphys = tid & 3;
  const int c2 = ((sphys ^ ((r2 >> 1) & 3)) * 8);        // swizzled global col
  const __bf16* a0 = A + (size_t)(m0 + r2) * kD + c2;
  const __bf16* a1 = A + (size_t)(m0 + 64 + r2) * kD + c2;
  const __bf16* b0 = B + (size_t)(n0 + r2) * kD + c2;    // r2<64 rows for B
  const int dstA0 = r2*32 + sphys*8;                     // A region: 0..4095 elems
  const int dstA1 = (64 + r2)*32 + sphys*8;
  const int dstB  = r2*32 + sphys*8;                     // B region: 0..2047 elems
  const int lr = lane & 15;
  const int tslot = (((lane >> 4) ^ ((lr >> 1) & 3)) * 8);

  auto stage = [&](__bf16* buf, int k0){
    gload16(a0 + k0, buf + dstA0);
    gload16(a1 + k0, buf + dstA1);
    gload16(b0 + k0, buf + 4096 + dstB);
  };
  auto compute = [&](const __bf16* buf){
    const __bf16* As = buf;
    const __bf16* Bs = buf + 4096;
    bf16x8 af[2], bfr[4];
#pragma unroll
    for (int m = 0; m < 2; m++) af[m]  = *reinterpret_cast<const bf16x8*>(As + (wm + m*16 + lr)*32 + tslot);
#pragma unroll
    for (int n = 0; n < 4; n++) bfr[n] = *reinterpret_cast<const bf16x8*>(Bs + (n*16 + lr)*32 + tslot);
#pragma unroll
    for (int n = 0; n < 4; n++)
#pragma unroll
      for (int m = 0; m < 2; m++)
        acc[n][m] = __builtin_amdgcn_mfma_f32_16x16x32_bf16(bfr[n], af[m], acc[n][m], 0, 0, 0);
  };

  __bf16* bc = smem;              // 6144 elems (12KB) per buffer
  __bf16* bn = smem + 6144;
  __bf16* bs = smem + 12288;

  constexpr int NT = kD / 32;
  stage(bc, 0);
  stage(bn, 32);
  for (int t = 0; t < NT - 2; ++t){
    stage(bs, (t + 2) * 32);
    asm volatile("s_waitcnt vmcnt(6)" ::: "memory");
    __builtin_amdgcn_s_barrier();
    compute(bc);
    __builtin_amdgcn_s_barrier();
    __bf16* tmp = bc; bc = bn; bn = bs; bs = tmp;
  }
  asm volatile("s_waitcnt vmcnt(3)" ::: "memory");
  __builtin_amdgcn_s_barrier();
  compute(bc);
  asm volatile("s_waitcnt vmcnt(0)" ::: "memory");
  __builtin_amdgcn_s_barrier();
  compute(bn);
}

// epilogue (swapped operands): row = m0+wm+m*16+(lane&15),
// cols = n0+n*16+(lane>>4)*4 + r  (packed bf16x4 store)

// ---------------- combine: Bmat[s] = Wk[s] @ Wq[s]^T (= Ws^T), bf16 out ----------------
__global__ __launch_bounds__(256) void combine_gemm(
    const __bf16* __restrict__ Wb, __bf16* __restrict__ Bmat)
{
  int bx, by, bz; xcd_remap(16, 8, 3, bx, by, bz);
  int s = bz;
  const __bf16* A = Wb + (size_t)(2*s+1) * kD * kD;
  const __bf16* B = Wb + (size_t)(2*s)   * kD * kD;
  __bf16* O = Bmat + (size_t)s * kD * kD;
  int m0 = by * 128, n0 = bx * 64;
  __shared__ __bf16 smem[3*6144];
  f32x4 acc[4][2] = {};
  gemm_core_n64(A, B, m0, n0, acc, smem);
  const int lane = threadIdx.x & 63, wid = threadIdx.x >> 6;
  const int wm = wid * 32;
  const int row_l = wm + (lane & 15), col_l = ((lane >> 4) << 2);
#pragma unroll
  for (int n = 0; n < 4; n++)
#pragma unroll
    for (int m = 0; m < 2; m++){
      int row = m0 + row_l + m*16;
      int colb = n0 + col_l + n*16;
      bf16x4 o;
#pragma unroll
      for (int r = 0; r < 4; r++) o[r] = (__bf16)acc[n][m][r];
      *reinterpret_cast<bf16x4*>(O + (size_t)row * kD + colb) = o;
    }
}

// ---------------- proj: P[s] = xb @ Ws (early-exit on non-false stripes) ----------------
__global__ __launch_bounds__(256) void proj_gemm(
    const __bf16* __restrict__ xb, const __bf16* __restrict__ Bmat,
    const int* __restrict__ nfs, __bf16* __restrict__ P, int b0, int cs)
{
  int bx, by, bz; xcd_remap(16, gridDim.y, 3, bx, by, bz);
  int z = bz;
  int m0 = by * 128, n0 = bx * 64;
  int bi = m0 >> 9, stripe = (m0 >> 7) & 3;
  if (nfs[(b0 + bi)*4 + stripe] == 0) return;
  const __bf16* A = xb + (size_t)b0 * kL * kD;
  const __bf16* B = Bmat + (size_t)z * kD * kD;
  __shared__ __bf16 smem[3*6144];
  f32x4 acc[4][2] = {};
  gemm_core_n64(A, B, m0, n0, acc, smem);
  __bf16* O = P + (size_t)z * cs * kL * kD;
  const int lane = threadIdx.x & 63, wid = threadIdx.x >> 6;
  const int wm = wid * 32;
  const int row_l = wm + (lane & 15), col_l = ((lane >> 4) << 2);
#pragma unroll
  for (int n = 0; n < 4; n++)
#pragma unroll
    for (int m = 0; m < 2; m++){
      int row = m0 + row_l + m*16;
      int colb = n0 + col_l + n*16;
      bf16x4 o;
#pragma unroll
      for (int r = 0; r < 4; r++) o[r] = (__bf16)acc[n][m][r];
      *reinterpret_cast<bf16x4*>(O + (size_t)row * kD + colb) = o;
    }
}

// ---------------- score: S[s][bi] = P @ xb^T * scale, bf16 out ----------------
__global__ __launch_bounds__(256) void score_gemm(
    const __bf16* __restrict__ P, const __bf16* __restrict__ xb,
    const int* __restrict__ nfs, const int* __restrict__ nos,
    __bf16* __restrict__ S, int b0, int cs)
{
  int bx, by, bz; xcd_remap(8, 4, gridDim.z, bx, by, bz);
  int s = bz % 3, bi = bz / 3;
  int b = b0 + bi;
  if (nfs[b*4 + by] == 0 || nos[b*4 + (bx >> 1)] == 0) return;
  int m0 = by * 128, n0 = bx * 64;
  const __bf16* A = P + ((size_t)s * cs + bi) * kL * kD;
  const __bf16* B = xb + (size_t)b * kL * kD;
  __bf16* O = S + ((size_t)s * cs + bi) * kL * kL;
  __shared__ __bf16 smem[3*6144];
  f32x4 acc[4][2] = {};
  gemm_core_n64(A, B, m0, n0, acc, smem);
  const int lane = threadIdx.x & 63, wid = threadIdx.x >> 6;
  const int wm = wid * 32;
  const int row_l = wm + (lane & 15), col_l = ((lane >> 4) << 2);
#pragma unroll
  for (int n = 0; n < 4; n++)
#pragma unroll
    for (int m = 0; m < 2; m++){
      int row = m0 + row_l + m*16;
      int colb = n0 + col_l + n*16;
      bf16x4 o;
#pragma unroll
      for (int r = 0; r < 4; r++) o[r] = (__bf16)(acc[n][m][r] * SCALE);
      *reinterpret_cast<bf16x4*>(O + (size_t)row * kL + colb) = o;
    }
}

// ---------------- wave-per-row masked softmax + gate combine (bf16 scores) ----------------
__global__ __launch_bounds__(256) void softmax_combine(
    const __bf16* __restrict__ S, const float* __restrict__ gate,
    const unsigned char* __restrict__ om, const int* __restrict__ n_om,
    const int* __restrict__ nfs,
    const float* __restrict__ tokc, const float* __restrict__ scon_s,
    float* __restrict__ c_sup, float* __restrict__ c_rep, int b0, int cs)
{
  int bi = blockIdx.y, b = b0 + bi;
  if (n_om[b] == 0) return;
  int i_base = blockIdx.x * 32;
  if (nfs[b*4 + (i_base >> 7)] == 0) return;
  int t = threadIdx.x, w = t >> 6, lane = t & 63;
  int c0 = lane * 8;
  const __bf16* ssup = S + ((size_t)0 * cs + bi) * (size_t)kL * kL;
  const __bf16* scon = S + ((size_t)1 * cs + bi) * (size_t)kL * kL;
  const __bf16* srep = S + ((size_t)2 * cs + bi) * (size_t)kL * kL;
  unsigned long long omv = *reinterpret_cast<const unsigned long long*>(om + (size_t)b*kL + c0);
  float csup_c[8], crep_c[8], ccon_c[8];
  bool msk[8];
#pragma unroll
  for (int u = 0; u < 8; u++){
    msk[u] = ((omv >> (8*u)) & 1ull) != 0;
    csup_c[u] = SCALE * tokc[0*kNT + b*kL + c0 + u];
    crep_c[u] = SCALE * tokc[1*kNT + b*kL + c0 + u];
    ccon_c[u] = SCALE * tokc[2*kNT + b*kL + c0 + u];
  }
  float sconst = SCALE * scon_s[0];
  float accS[8] = {}, accR[8] = {};
  int i0w = i_base + w * 8;
  for (int ii = 0; ii < 8; ii++){
    int i = i0w + ii;
    float g = gate[(size_t)b*kL + i];
    if (!(g > 0.f)) continue;
    float rcon_i = SCALE * tokc[3*kNT + b*kL + i] + sconst;
    size_t base = (size_t)i * kL + c0;
    bf16x8 sb = *reinterpret_cast<const bf16x8*>(ssup + base);
    bf16x8 cb = *reinterpret_cast<const bf16x8*>(scon + base);
    bf16x8 rb = *reinterpret_cast<const bf16x8*>(srep + base);
    float vs[8], vr[8];
#pragma unroll
    for (int u = 0; u < 8; u++){
      float sv = (float)sb[u], cv = (float)cb[u], rv = (float)rb[u];
      vs[u] = msk[u] ? (sv + csup_c[u]) : NEGF;
      vr[u] = msk[u] ? (rv + crep_c[u] + fast_tanh(cv + ccon_c[u] + rcon_i)) : NEGF;
    }
    float ms = vs[0], mr = vr[0];
#pragma unroll
    for (int u = 1; u < 8; u++){ ms = fmaxf(ms, vs[u]); mr = fmaxf(mr, vr[u]); }
    ms = wave_max(ms); mr = wave_max(mr);
    float es[8], er[8], zs = 0.f, zr = 0.f;
#pragma unroll
    for (int u = 0; u < 8; u++){
      es[u] = __expf(vs[u] - ms); er[u] = __expf(vr[u] - mr);
      zs += es[u]; zr += er[u];
    }
    zs = wave_sum(zs); zr = wave_sum(zr);
    float gs = g / zs, gr = g / zr;
#pragma unroll
    for (int u = 0; u < 8; u++){ accS[u] += gs * es[u]; accR[u] += gr * er[u]; }
  }
  __shared__ float lsS[4][kL];
  __shared__ float lsR[4][kL];
#pragma unroll
  for (int u = 0; u < 8; u++){ lsS[w][c0+u] = accS[u]; lsR[w][c0+u] = accR[u]; }
  __syncthreads();
  int col0 = t, col1 = t + 256;
  float vS0 = lsS[0][col0]+lsS[1][col0]+lsS[2][col0]+lsS[3][col0];
  float vR0 = lsR[0][col0]+lsR[1][col0]+lsR[2][col0]+lsR[3][col0];
  float vS1 = lsS[0][col1]+lsS[1][col1]+lsS[2][col1]+lsS[3][col1];
  float vR1 = lsR[0][col1]+lsR[1][col1]+lsR[2][col1]+lsR[3][col1];
  atomicAdd(&c_sup[(size_t)b*kL + col0], vS0);
  atomicAdd(&c_rep[(size_t)b*kL + col0], vR0);
  atomicAdd(&c_sup[(size_t)b*kL + col1], vS1);
  atomicAdd(&c_rep[(size_t)b*kL + col1], vR1);
}

// ---------------- weighted sums over xb -> insG2[lz][b][3*kD] (no atomics) ----------------
__global__ __launch_bounds__(256) void vec_kernel(
    const __bf16* __restrict__ xb, const float* __restrict__ gate,
    const float* __restrict__ c_sup, const float* __restrict__ c_rep,
    float* __restrict__ insG2)
{
  int b = blockIdx.y, dq = blockIdx.x, lz = blockIdx.z;
  int tid = threadIdx.x;
  __shared__ float g_s[256], cs_s[256], cr_s[256];
  __shared__ float acc_s[3][256];
  {
    int l = lz*256 + tid;
    g_s[tid]  = gate[b*kL + l];
    cs_s[tid] = c_sup[b*kL + l];
    cr_s[tid] = c_rep[b*kL + l];
  }
  for (int j = tid; j < 768; j += 256) (&acc_s[0][0])[j] = 0.f;
  __syncthreads();
  int dg = tid & 31;
  int ls = tid >> 5;
  int d0 = dq*256 + dg*8;
  float a[8] = {}, r[8] = {}, s[8] = {};
  const __bf16* xp = xb + (size_t)b * kL * kD + (size_t)(lz*256) * kD + d0;
#pragma unroll 4
  for (int i = 0; i < 32; i++){
    int l = ls + i*8;
    bf16x8 v = *reinterpret_cast<const bf16x8*>(xp + (size_t)l * kD);
    float g = g_s[l], cr = cr_s[l], csv = cs_s[l];
#pragma unroll
    for (int u = 0; u < 8; u++){
      float xv = (float)v[u];
      a[u] = fmaf(g,   xv, a[u]);
      r[u] = fmaf(cr,  xv, r[u]);
      s[u] = fmaf(csv, xv, s[u]);
    }
  }
#pragma unroll
  for (int u = 0; u < 8; u++){
    atomicAdd(&acc_s[0][dg*8+u], a[u]);
    atomicAdd(&acc_s[1][dg*8+u], r[u]);
    atomicAdd(&acc_s[2][dg*8+u], s[u]);
  }
  __syncthreads();
  int d = dq*256 + tid;
  size_t base = ((size_t)(lz*kB + b)) * (size_t)(3*kD);
  insG2[base + 0*kD + d] = acc_s[0][tid];
  insG2[base + 1*kD + d] = acc_s[1][tid];
  insG2[base + 2*kD + d] = acc_s[2][tid];
}

// ---------------- FFN1: hpart[y][b][kD] (no atomics) ----------------
__global__ __launch_bounds__(256) void ffn1_kernel(
    const float* __restrict__ insG2, const float* __restrict__ w_f1, float* __restrict__ hpart)
{
  int bx = blockIdx.x, by = blockIdx.y;
  int tid = threadIdx.x, lane = tid & 63, bg = tid >> 6;
  int k0 = by * 64;
  __shared__ float ins_s[64][32];
  {
    int b = tid >> 3, kk = (tid & 7) * 8;
    const float* p0 = insG2 + (size_t)b        * (size_t)(3*kD) + k0 + kk;
    const float* p1 = insG2 + (size_t)(kB + b) * (size_t)(3*kD) + k0 + kk;
    f32x4 v0a = *reinterpret_cast<const f32x4*>(p0);
    f32x4 v0b = *reinterpret_cast<const f32x4*>(p0 + 4);
    f32x4 v1a = *reinterpret_cast<const f32x4*>(p1);
    f32x4 v1b = *reinterpret_cast<const f32x4*>(p1 + 4);
#pragma unroll
    for (int i = 0; i < 4; i++){
      ins_s[kk+i][b]   = v0a[i] + v1a[i];
      ins_s[kk+4+i][b] = v0b[i] + v1b[i];
    }
  }
  __syncthreads();
  int c0 = bx*256 + lane*4;
  float acc[4][8] = {};
  const float* wp = w_f1 + (size_t)k0 * kD + c0;
#pragma unroll 4
  for (int k = 0; k < 64; k++){
    f32x4 w = *reinterpret_cast<const f32x4*>(wp + (size_t)k * kD);
    f32x4 i0 = *reinterpret_cast<const f32x4*>(&ins_s[k][bg*8]);
    f32x4 i1 = *reinterpret_cast<const f32x4*>(&ins_s[k][bg*8+4]);
#pragma unroll
    for (int c = 0; c < 4; c++){
#pragma unroll
      for (int j = 0; j < 4; j++){
        acc[c][j]   = fmaf(w[c], i0[j], acc[c][j]);
        acc[c][4+j] = fmaf(w[c], i1[j], acc[c][4+j]);
      }
    }
  }
  float* hp = hpart + (size_t)by * kB * kD + bx*256;
#pragma unroll
  for (int j = 0; j < 8; j++){
    f32x4 o;
#pragma unroll
    for (int c = 0; c < 4; c++) o[c] = acc[c][j];
    *reinterpret_cast<f32x4*>(hp + (size_t)(bg*8 + j) * kD + lane*4) = o;
  }
}

// ---------------- hreduce: hT2[b][kD] = relu(sum_y hpart + b_f1) ----------------
__global__ __launch_bounds__(256) void hreduce_kernel(
    const float* __restrict__ hpart, const float* __restrict__ b_f1, float* __restrict__ hT2)
{
  int idx = blockIdx.x * 256 + threadIdx.x;
  size_t off = (size_t)idx * 4;
  f32x4 s = {};
  for (int y = 0; y < 48; y++)
    s += *reinterpret_cast<const f32x4*>(hpart + (size_t)y * kB * kD + off);
  int k = (int)(off & (kD - 1));
  f32x4 bv = *reinterpret_cast<const f32x4*>(b_f1 + k);
  f32x4 o;
#pragma unroll
  for (int i = 0; i < 4; i++) o[i] = fmaxf(s[i] + bv[i], 0.f);
  *reinterpret_cast<f32x4*>(hT2 + off) = o;
}

// ---------------- FFN2: f2part[y][b][kD] (no atomics) ----------------
__global__ __launch_bounds__(256) void ffn2_kernel(
    const float* __restrict__ hT2, const float* __restrict__ w_f2, float* __restrict__ f2part)
{
  int bx = blockIdx.x, by = blockIdx.y;
  int tid = threadIdx.x, lane = tid & 63, bg = tid >> 6;
  int k0 = by * 64;
  __shared__ float hs[64][32];
  {
    int b = tid >> 3, kk = (tid & 7) * 8;
    const float* p = hT2 + (size_t)b * kD + k0 + kk;
    f32x4 va = *reinterpret_cast<const f32x4*>(p);
    f32x4 vb = *reinterpret_cast<const f32x4*>(p + 4);
#pragma unroll
    for (int i = 0; i < 4; i++){ hs[kk+i][b] = va[i]; hs[kk+4+i][b] = vb[i]; }
  }
  __syncthreads();
  int c0 = bx*256 + lane*4;
  float acc[4][8] = {};
  const float* wp = w_f2 + (size_t)k0 * kD + c0;
#pragma unroll 4
  for (int k = 0; k < 64; k++){
    f32x4 w = *reinterpret_cast<const f32x4*>(wp + (size_t)k * kD);
    f32x4 i0 = *reinterpret_cast<const f32x4*>(&hs[k][bg*8]);
    f32x4 i1 = *reinterpret_cast<const f32x4*>(&hs[k][bg*8+4]);
#pragma unroll
    for (int c = 0; c < 4; c++){
#pragma unroll
      for (int j = 0; j < 4; j++){
        acc[c][j]   = fmaf(w[c], i0[j], acc[c][j]);
        acc[c][4+j] = fmaf(w[c], i1[j], acc[c][4+j]);
      }
    }
  }
  float* fp = f2part + (size_t)by * kB * kD + bx*256;
#pragma unroll
  for (int j = 0; j < 8; j++){
    f32x4 o;
#pragma unroll
    for (int c = 0; c < 4; c++) o[c] = acc[c][j];
    *reinterpret_cast<f32x4*>(fp + (size_t)(bg*8 + j) * kD + lane*4) = o;
  }
}

// ---------------- LayerNorm (reduces 16 f2 partials, adds b_f2) ----------------
__global__ __launch_bounds__(256) void ln_kernel(
    const float* __restrict__ f2part, const float* __restrict__ b_f2,
    const float* __restrict__ g, const float* __restrict__ bta, float* __restrict__ out)
{
  int b = blockIdx.x, t = threadIdx.x;
  __shared__ float red[4];
  float v[4]; float s1 = 0.f, s2 = 0.f;
#pragma unroll
  for (int u = 0; u < 4; u++){
    int o = t + u*256;
    float acc = b_f2[o];
    for (int y = 0; y < 16; y++)
      acc += f2part[(size_t)y * kB * kD + (size_t)b * kD + o];
    v[u] = acc;
    s1 += v[u]; s2 += v[u]*v[u];
  }
  s1 = blk_sum<4>(s1, red);
  s2 = blk_sum<4>(s2, red);
  float mu = s1 * (1.f/(float)kD);
  float var = s2 * (1.f/(float)kD) - mu*mu;
  float inv = rsqrtf(var + 1e-5f);
#pragma unroll
  for (int u = 0; u < 4; u++){
    int o = t + u*256;
    out[(size_t)b*kD + o] = (v[u] - mu) * inv * g[o] + bta[o];
  }
}

// ---------------- host launch ----------------
extern "C" void kernel_launch(void* const* d_in, const int* in_sizes, int n_in,
                              void* d_out, int out_size, void* d_ws, size_t ws_size,
                              hipStream_t stream)
{
  const float* x      = (const float*)d_in[0];
  const int*   ids    = (const int*)d_in[1];
  const int*   pad_p  = (const int*)d_in[2];
  const int*   sep_p  = (const int*)d_in[3];
  const float* w_anom = (const float*)d_in[4];
  const float* b_anom = (const float*)d_in[5];
  const float* w_sq = (const float*)d_in[6];  const float* b_sq = (const float*)d_in[7];
  const float* w_sk = (const float*)d_in[8];  const float* b_sk = (const float*)d_in[9];
  const float* w_cq = (const float*)d_in[10]; const float* b_cq = (const float*)d_in[11];
  const float* w_ck = (const float*)d_in[12]; const float* b_ck = (const float*)d_in[13];
  const float* w_rq = (const float*)d_in[14]; const float* b_rq = (const float*)d_in[15];
  const float* w_rk = (const float*)d_in[16]; const float* b_rk = (const float*)d_in[17];
  const float* w_f1 = (const float*)d_in[18]; const float* b_f1 = (const float*)d_in[19];
  const float* w_f2 = (const float*)d_in[20]; const float* b_f2 = (const float*)d_in[21];
  const float* lng  = (const float*)d_in[22]; const float* lnb  = (const float*)d_in[23];
  float* out = (float*)d_out;

  char* p = (char*)d_ws;
  auto carve = [&](size_t bytes) -> void* {
    void* r = (void*)p; p += (bytes + 255) & ~(size_t)255; return r;
  };
  int* n_fm = (int*)carve(kB*4);
  int* n_om = (int*)carve(kB*4);
  int* nfs  = (int*)carve(kB*4*4);
  int* nos  = (int*)carve(kB*4*4);
  unsigned char* fm = (unsigned char*)carve(kB*kL);
  unsigned char* om = (unsigned char*)carve(kB*kL);
  float* logits = (float*)carve((size_t)kNT*4);
  float* gate   = (float*)carve((size_t)kNT*4);
  float* c_sup  = (float*)carve((size_t)kNT*4);
  float* c_rep  = (float*)carve((size_t)kNT*4);
  float* tokc   = (float*)carve((size_t)4*kNT*4);
  float* vecs4  = (float*)carve((size_t)4*kD*4);
  float* scon_s = (float*)carve(256);
  float* insG2  = (float*)carve((size_t)2*kB*3*kD*4);
  float* hpart  = (float*)carve((size_t)48*kB*kD*4);
  float* hT2    = (float*)carve((size_t)kB*kD*4);
  float* f2part = (float*)carve((size_t)16*kB*kD*4);
  __bf16* Bmat = (__bf16*)carve((size_t)3*kD*kD*2);
  __bf16* xb   = (__bf16*)carve((size_t)kNT*kD*2);

  size_t used = (size_t)(p - (char*)d_ws);
  size_t wb_bytes = (size_t)6*kD*kD*2;
  size_t per_chunk = (size_t)3*kL*kD*2 + (size_t)3*kL*kL*2;
  long avail = (long)ws_size - (long)used - 8192;
  __bf16 *Wb, *P, *scores;
  int chunkB;
  if (avail >= (long)wb_bytes && avail >= (long)per_chunk){
    chunkB = (int)(avail / (long)per_chunk);
    if (chunkB > kB) chunkB = kB;
    if ((size_t)chunkB * per_chunk < wb_bytes){
      Wb = (__bf16*)carve(wb_bytes);
      used = (size_t)(p - (char*)d_ws);
      avail = (long)ws_size - (long)used - 8192;
      chunkB = (avail > 0) ? (int)(avail / (long)per_chunk) : 1;
      if (chunkB < 1) chunkB = 1;
      if (chunkB > kB) chunkB = kB;
      P = (__bf16*)p;
    } else {
      Wb = (__bf16*)p; P = (__bf16*)p;
    }
  } else {
    Wb = (__bf16*)carve(wb_bytes);
    used = (size_t)(p - (char*)d_ws);
    avail = (long)ws_size - (long)used - 8192;
    chunkB = (avail > 0) ? (int)(avail / (long)per_chunk) : 1;
    if (chunkB < 1) chunkB = 1;
    if (chunkB > kB) chunkB = kB;
    P = (__bf16*)p;
  }
  scores = P + (size_t)3*chunkB*kL*kD;

  masks_kernel<<<kB, 256, 0, stream>>>(ids, pad_p, sep_p, n_fm, n_om, nfs, nos, fm, om, c_sup, c_rep);
  conv_w_kernel<<<dim3(kD*kD/2048, 6), 256, 0, stream>>>(w_sq, w_sk, w_cq, w_ck, w_rq, w_rk, Wb);
  wb_vec_kernel<<<dim3(kD/4, 5), 256, 0, stream>>>(w_sk, b_sq, w_rk, b_rq, w_ck, b_cq, w_cq, b_ck, vecs4, scon_s);
  prep_x_kernel<<<kNT/2, 256, 0, stream>>>(x, w_anom, b_anom, vecs4, xb, logits, tokc);
  gate_kernel<<<kB, 256, 0, stream>>>(logits, fm, n_fm, gate);
  combine_gemm<<<dim3(16, 8, 3), 256, 0, stream>>>(Wb, Bmat);

  for (int b0 = 0; b0 < kB; b0 += chunkB){
    int cs = chunkB; if (b0 + cs > kB) cs = kB - b0;
    proj_gemm<<<dim3(16, cs*4, 3), 256, 0, stream>>>(xb, Bmat, nfs, P, b0, cs);
    score_gemm<<<dim3(8, 4, cs*3), 256, 0, stream>>>(P, xb, nfs, nos, scores, b0, cs);
    softmax_combine<<<dim3(kL/32, cs), 256, 0, stream>>>(scores, gate, om, n_om, nfs,
        tokc, scon_s, c_sup, c_rep, b0, cs);
  }

  vec_kernel<<<dim3(4, kB, 2), 256, 0, stream>>>(xb, gate, c_sup, c_rep, insG2);
  ffn1_kernel<<<dim3(4, 48), 256, 0, stream>>>(insG2, w_f1, hpart);
  hreduce_kernel<<<32, 256, 0, stream>>>(hpart, b_f1, hT2);
  ffn2_kernel<<<dim3(4, 16), 256, 0, stream>>>(hT2, w_f2, f2part);
  ln_kernel<<<kB, 256, 0, stream>>>(f2part, b_f2, lng, lnb, out);
}

// Round 14
// 237.526 us; speedup vs baseline: 1.0784x; 1.0784x over previous
//
#include <hip/hip_runtime.h>
#include <cmath>
#include <cstdint>

static constexpr int kB = 32;
static constexpr int kL = 512;
static constexpr int kD = 1024;
static constexpr int kNT = kB * kL;      // total tokens
#define NEGF (-9.0e15f)
#define SCALE 0.03125f                   // 1/sqrt(1024)

typedef __bf16 bf16x8 __attribute__((ext_vector_type(8)));
typedef __bf16 bf16x4 __attribute__((ext_vector_type(4)));
typedef float f32x4 __attribute__((ext_vector_type(4)));

// ---------------- helpers ----------------
__device__ __forceinline__ float wave_sum(float v){
#pragma unroll
  for(int o=32;o>0;o>>=1) v += __shfl_xor(v,o,64);
  return v;
}
__device__ __forceinline__ float wave_max(float v){
#pragma unroll
  for(int o=32;o>0;o>>=1) v = fmaxf(v,__shfl_xor(v,o,64));
  return v;
}
template<int NW>
__device__ __forceinline__ float blk_sum(float v, float* red){
  v = wave_sum(v);
  __syncthreads();
  if((threadIdx.x&63)==0) red[threadIdx.x>>6]=v;
  __syncthreads();
  float r = red[0];
#pragma unroll
  for(int i=1;i<NW;i++) r += red[i];
  return r;
}
template<int NW>
__device__ __forceinline__ float blk_max(float v, float* red){
  v = wave_max(v);
  __syncthreads();
  if((threadIdx.x&63)==0) red[threadIdx.x>>6]=v;
  __syncthreads();
  float r = red[0];
#pragma unroll
  for(int i=1;i<NW;i++) r = fmaxf(r, red[i]);
  return r;
}

__device__ __forceinline__ void gload16(const void* g, void* l){
  __builtin_amdgcn_global_load_lds(
      (const __attribute__((address_space(1))) void*)g,
      (__attribute__((address_space(3))) void*)l, 16, 0, 0);
}

__device__ __forceinline__ float fast_tanh(float x){
  return 1.f - 2.f / (__expf(2.f * x) + 1.f);
}

// bijective XCD swizzle (m204)
__device__ __forceinline__ void xcd_remap(int gx, int gy, int gz, int& ox, int& oy, int& oz){
  int flat = blockIdx.x + gx*(blockIdx.y + gy*blockIdx.z);
  int nwg = gx*gy*gz;
  int c = flat & 7, j = flat >> 3;
  int logical = c*(nwg >> 3) + j;
  ox = logical % gx; int rest = logical / gx;
  oy = rest % gy; oz = rest / gy;
}

// ---------------- masks / sep_pos / stripe counts / c init ----------------
__global__ __launch_bounds__(256) void masks_kernel(
    const int* __restrict__ ids, const int* __restrict__ pad_p, const int* __restrict__ sep_p,
    int* __restrict__ n_fm, int* __restrict__ n_om,
    int* __restrict__ nfs, int* __restrict__ nos,
    unsigned char* __restrict__ fm, unsigned char* __restrict__ om,
    float* __restrict__ c_sup, float* __restrict__ c_rep)
{
  int b = blockIdx.x, t = threadIdx.x;
  int pad = pad_p[0], sep = sep_p[0];
  __shared__ int s_first, s_vl, s_nf, s_no, s_sp;
  __shared__ int s_nfs[4], s_nos[4];
  if (t == 0){ s_first = kL; s_vl = 0; s_nf = 0; s_no = 0; }
  if (t < 4){ s_nfs[t] = 0; s_nos[t] = 0; }
  __syncthreads();
  int id0 = ids[b*kL + t], id1 = ids[b*kL + t + 256];
  int v0 = (id0 != pad) ? 1 : 0, v1 = (id1 != pad) ? 1 : 0;
  int fl = kL;
  if (id0 == sep) fl = t;
  if (id1 == sep && (t + 256) < fl) fl = t + 256;
  atomicMin(&s_first, fl);
  atomicAdd(&s_vl, v0 + v1);
  __syncthreads();
  if (t == 0){
    int vl = s_vl;
    int fb = vl / 2; if (fb < 1) fb = 1; if (fb > kL - 2) fb = kL - 2;
    s_sp = (s_first < kL) ? s_first : fb;
  }
  __syncthreads();
  int sp = s_sp;
  int f0 = ((t < sp) && v0) ? 1 : 0,         o0 = ((t > sp) && v0) ? 1 : 0;
  int f1 = (((t+256) < sp) && v1) ? 1 : 0,   o1 = (((t+256) > sp) && v1) ? 1 : 0;
  fm[b*kL+t] = (unsigned char)f0; fm[b*kL+t+256] = (unsigned char)f1;
  om[b*kL+t] = (unsigned char)o0; om[b*kL+t+256] = (unsigned char)o1;
  atomicAdd(&s_nf, f0 + f1); atomicAdd(&s_no, o0 + o1);
  if (f0) atomicAdd(&s_nfs[t>>7], 1);
  if (o0) atomicAdd(&s_nos[t>>7], 1);
  if (f1) atomicAdd(&s_nfs[(t+256)>>7], 1);
  if (o1) atomicAdd(&s_nos[(t+256)>>7], 1);
  __syncthreads();
  if (t == 0){ n_fm[b] = s_nf; n_om[b] = s_no; }
  if (t < 4){ nfs[b*4 + t] = s_nfs[t]; nos[b*4 + t] = s_nos[t]; }
  float u = (s_no == 0 && s_nf > 0) ? (1.0f/(float)kL) : 0.0f;
  c_sup[b*kL+t] = u; c_sup[b*kL+t+256] = u;
  c_rep[b*kL+t] = u; c_rep[b*kL+t+256] = u;
}

// ---------------- W f32 -> bf16 (6 mats) ----------------
__global__ __launch_bounds__(256) void conv_w_kernel(
    const float* w0, const float* w1, const float* w2,
    const float* w3, const float* w4, const float* w5, __bf16* __restrict__ Wb)
{
  const float* W;
  switch (blockIdx.y){
    case 0: W = w0; break; case 1: W = w1; break; case 2: W = w2; break;
    case 3: W = w3; break; case 4: W = w4; break; default: W = w5; break;
  }
  size_t i = ((size_t)blockIdx.x * 256 + threadIdx.x) * 8;
  float4 a = *reinterpret_cast<const float4*>(W + i);
  float4 b = *reinterpret_cast<const float4*>(W + i + 4);
  bf16x8 v;
  v[0]=(__bf16)a.x; v[1]=(__bf16)a.y; v[2]=(__bf16)a.z; v[3]=(__bf16)a.w;
  v[4]=(__bf16)b.x; v[5]=(__bf16)b.y; v[6]=(__bf16)b.z; v[7]=(__bf16)b.w;
  *reinterpret_cast<bf16x8*>(Wb + (size_t)blockIdx.y * kD * kD + i) = v;
}

// ---------------- bias vectors: vecs4[m]=M_m@v_m (m<4), m==4: scon = bcq.bck ----------------
__global__ __launch_bounds__(256) void wb_vec_kernel(
    const float* wsk, const float* bsq, const float* wrk, const float* brq,
    const float* wck, const float* bcq, const float* wcq, const float* bck,
    float* __restrict__ vecs4, float* __restrict__ scon_s)
{
  int m = blockIdx.y;
  int lane = threadIdx.x & 63;
  if (m == 4){
    if (blockIdx.x != 0 || threadIdx.x >= 64) return;
    float acc = 0.f;
    for (int i = lane; i < kD; i += 64) acc += bcq[i]*bck[i];
    acc = wave_sum(acc);
    if (lane == 0) scon_s[0] = acc;
    return;
  }
  const float* M; const float* v;
  switch(m){
    case 0: M=wsk; v=bsq; break; case 1: M=wrk; v=brq; break;
    case 2: M=wck; v=bcq; break; default: M=wcq; v=bck; break;
  }
  int e = blockIdx.x*4 + (threadIdx.x>>6);
  const float4* Mr = reinterpret_cast<const float4*>(M + (size_t)e*kD);
  const float4* vr = reinterpret_cast<const float4*>(v);
  float acc = 0.f;
#pragma unroll 4
  for (int i = lane; i < kD/4; i += 64){
    float4 a = Mr[i], w = vr[i];
    acc += a.x*w.x + a.y*w.y + a.z*w.z + a.w*w.w;
  }
  acc = wave_sum(acc);
  if (lane == 0) vecs4[m*kD + e] = acc;
}

// ---------------- fused: x->bf16 + anomaly logits + 4 per-token dots ----------------
__global__ __launch_bounds__(256) void prep_x_kernel(
    const float* __restrict__ x, const float* __restrict__ w_anom, const float* __restrict__ b_anom,
    const float* __restrict__ vecs4, __bf16* __restrict__ xb,
    float* __restrict__ logits, float* __restrict__ tokc)
{
  int w = threadIdx.x >> 6;
  int row = blockIdx.x*2 + (threadIdx.x>>7);
  int li = threadIdx.x & 127;
  size_t base = (size_t)row*kD + li*8;
  float4 a = *reinterpret_cast<const float4*>(x + base);
  float4 b4 = *reinterpret_cast<const float4*>(x + base + 4);
  bf16x8 v;
  v[0]=(__bf16)a.x; v[1]=(__bf16)a.y; v[2]=(__bf16)a.z; v[3]=(__bf16)a.w;
  v[4]=(__bf16)b4.x; v[5]=(__bf16)b4.y; v[6]=(__bf16)b4.z; v[7]=(__bf16)b4.w;
  *reinterpret_cast<bf16x8*>(xb + base) = v;

  const float* vp[5] = {w_anom, vecs4, vecs4+kD, vecs4+2*kD, vecs4+3*kD};
  float d[5];
#pragma unroll
  for (int j = 0; j < 5; j++){
    float4 wa = *reinterpret_cast<const float4*>(vp[j] + li*8);
    float4 wb2 = *reinterpret_cast<const float4*>(vp[j] + li*8 + 4);
    d[j] = a.x*wa.x + a.y*wa.y + a.z*wa.z + a.w*wa.w
         + b4.x*wb2.x + b4.y*wb2.y + b4.z*wb2.z + b4.w*wb2.w;
    d[j] = wave_sum(d[j]);
  }
  __shared__ float red[4][5];
  if ((threadIdx.x & 63) == 0){
#pragma unroll
    for (int j = 0; j < 5; j++) red[w][j] = d[j];
  }
  __syncthreads();
  if ((threadIdx.x & 127) == 0){
    int w0 = (threadIdx.x >> 7) * 2;
    logits[row] = red[w0][0] + red[w0+1][0] + b_anom[0];
#pragma unroll
    for (int j = 1; j < 5; j++)
      tokc[(j-1)*kNT + row] = red[w0][j] + red[w0+1][j];
  }
}

// ---------------- gate softmax ----------------
__global__ __launch_bounds__(256) void gate_kernel(const float* __restrict__ logits,
    const unsigned char* __restrict__ fm, const int* __restrict__ n_fm, float* __restrict__ gate)
{
  int b = blockIdx.x, t = threadIdx.x;
  __shared__ float red[4];
  if (n_fm[b] == 0){ gate[b*kL+t] = 0.f; gate[b*kL+t+256] = 0.f; return; }
  int f0 = fm[b*kL+t], f1 = fm[b*kL+t+256];
  float l0 = f0 ? logits[b*kL+t]     : -INFINITY;
  float l1 = f1 ? logits[b*kL+t+256] : -INFINITY;
  float m = blk_max<4>(fmaxf(l0, l1), red);
  float e0 = f0 ? __expf(l0 - m) : 0.f;
  float e1 = f1 ? __expf(l1 - m) : 0.f;
  float Z = blk_sum<4>(e0 + e1, red);
  gate[b*kL+t]     = e0 / Z;
  gate[b*kL+t+256] = e1 / Z;
}

// ---------------- 128x128 NT GEMM core (3-buffer counted-vmcnt pipeline) ----------------
// PROVEN R4-R12 structure: stage(t+2); vmcnt(8) BEFORE barrier (the barrier
// globalizes each wave's completion certificate for tile t).
__device__ __forceinline__ void gemm_core_p3(
    const __bf16* __restrict__ A, const __bf16* __restrict__ B,
    int m0, int n0, f32x4 (&acc)[4][4], __bf16* smem)
{
  const int tid = threadIdx.x, lane = tid & 63, wid = tid >> 6;
  const int wm = (wid >> 1) * 64, wn = (wid & 1) * 64;
  const int r2 = tid >> 2, sphys = tid & 3;
  const int c2 = ((sphys ^ ((r2 >> 1) & 3)) * 8);        // swizzled global col
  const __bf16* a0 = A + (size_t)(m0 + r2) * kD + c2;
  const __bf16* a1 = A + (size_t)(m0 + 64 + r2) * kD + c2;
  const __bf16* b0 = B + (size_t)(n0 + r2) * kD + c2;
  const __bf16* b1 = B + (size_t)(n0 + 64 + r2) * kD + c2;
  const int dst0 = r2*32 + sphys*8;                      // linear LDS dest (tid*16B)
  const int dst1 = (64 + r2)*32 + sphys*8;
  const int lr = lane & 15;
  const int tslot = (((lane >> 4) ^ ((lr >> 1) & 3)) * 8);

  auto stage = [&](__bf16* buf, int k0){
    gload16(a0 + k0, buf + dst0);
    gload16(a1 + k0, buf + dst1);
    gload16(b0 + k0, buf + 4096 + dst0);
    gload16(b1 + k0, buf + 4096 + dst1);
  };
  auto compute = [&](const __bf16* buf){
    const __bf16* As = buf;
    const __bf16* Bs = buf + 4096;
    bf16x8 af[4], bfr[4];
#pragma unroll
    for (int m = 0; m < 4; m++) af[m]  = *reinterpret_cast<const bf16x8*>(As + (wm + m*16 + lr)*32 + tslot);
#pragma unroll
    for (int n = 0; n < 4; n++) bfr[n] = *reinterpret_cast<const bf16x8*>(Bs + (wn + n*16 + lr)*32 + tslot);
#pragma unroll
    for (int n = 0; n < 4; n++)
#pragma unroll
      for (int m = 0; m < 4; m++)
        acc[n][m] = __builtin_amdgcn_mfma_f32_16x16x32_bf16(bfr[n], af[m], acc[n][m], 0, 0, 0);
  };

  __bf16* bc = smem;
  __bf16* bn = smem + 8192;
  __bf16* bs = smem + 16384;

  constexpr int NT = kD / 32;
  stage(bc, 0);
  stage(bn, 32);
  for (int t = 0; t < NT - 2; ++t){
    stage(bs, (t + 2) * 32);
    asm volatile("s_waitcnt vmcnt(8)" ::: "memory");
    __builtin_amdgcn_s_barrier();
    compute(bc);
    __builtin_amdgcn_s_barrier();
    __bf16* tmp = bc; bc = bn; bn = bs; bs = tmp;
  }
  asm volatile("s_waitcnt vmcnt(4)" ::: "memory");
  __builtin_amdgcn_s_barrier();
  compute(bc);
  asm volatile("s_waitcnt vmcnt(0)" ::: "memory");
  __builtin_amdgcn_s_barrier();
  compute(bn);
}

// ---------------- combine: Bmat[s] = Wk[s] @ Wq[s]^T (= Ws^T), bf16 out ----------------
__global__ __launch_bounds__(256) void combine_gemm(
    const __bf16* __restrict__ Wb, __bf16* __restrict__ Bmat)
{
  int bx, by, bz; xcd_remap(8, 8, 3, bx, by, bz);
  int s = bz;
  const __bf16* A = Wb + (size_t)(2*s+1) * kD * kD;
  const __bf16* B = Wb + (size_t)(2*s)   * kD * kD;
  __bf16* O = Bmat + (size_t)s * kD * kD;
  int m0 = by * 128, n0 = bx * 128;
  __shared__ __bf16 smem[3*8192];
  f32x4 acc[4][4] = {};
  gemm_core_p3(A, B, m0, n0, acc, smem);
  const int lane = threadIdx.x & 63, wid = threadIdx.x >> 6;
  const int wm = (wid >> 1) * 64, wn = (wid & 1) * 64;
  const int row_l = wm + (lane & 15), col_l = wn + ((lane >> 4) << 2);
#pragma unroll
  for (int n = 0; n < 4; n++)
#pragma unroll
    for (int m = 0; m < 4; m++){
      int row = m0 + row_l + m*16;
      int colb = n0 + col_l + n*16;
      bf16x4 o;
#pragma unroll
      for (int r = 0; r < 4; r++) o[r] = (__bf16)acc[n][m][r];
      *reinterpret_cast<bf16x4*>(O + (size_t)row * kD + colb) = o;
    }
}

// ---------------- proj: P[s] = xb @ Ws (early-exit on non-false stripes) ----------------
__global__ __launch_bounds__(256) void proj_gemm(
    const __bf16* __restrict__ xb, const __bf16* __restrict__ Bmat,
    const int* __restrict__ nfs, __bf16* __restrict__ P, int b0, int cs)
{
  int bx, by, bz; xcd_remap(8, gridDim.y, 3, bx, by, bz);
  int z = bz;
  int m0 = by * 128, n0 = bx * 128;
  int bi = m0 >> 9, stripe = (m0 >> 7) & 3;
  if (nfs[(b0 + bi)*4 + stripe] == 0) return;
  const __bf16* A = xb + (size_t)b0 * kL * kD;
  const __bf16* B = Bmat + (size_t)z * kD * kD;
  __shared__ __bf16 smem[3*8192];
  f32x4 acc[4][4] = {};
  gemm_core_p3(A, B, m0, n0, acc, smem);
  __bf16* O = P + (size_t)z * cs * kL * kD;
  const int lane = threadIdx.x & 63, wid = threadIdx.x >> 6;
  const int wm = (wid >> 1) * 64, wn = (wid & 1) * 64;
  const int row_l = wm + (lane & 15), col_l = wn + ((lane >> 4) << 2);
#pragma unroll
  for (int n = 0; n < 4; n++)
#pragma unroll
    for (int m = 0; m < 4; m++){
      int row = m0 + row_l + m*16;
      int colb = n0 + col_l + n*16;
      bf16x4 o;
#pragma unroll
      for (int r = 0; r < 4; r++) o[r] = (__bf16)acc[n][m][r];
      *reinterpret_cast<bf16x4*>(O + (size_t)row * kD + colb) = o;
    }
}

// ---------------- score: S[s][bi] = P @ xb^T * scale, bf16 out ----------------
__global__ __launch_bounds__(256) void score_gemm(
    const __bf16* __restrict__ P, const __bf16* __restrict__ xb,
    const int* __restrict__ nfs, const int* __restrict__ nos,
    __bf16* __restrict__ S, int b0, int cs)
{
  int bx, by, bz; xcd_remap(4, 4, gridDim.z, bx, by, bz);
  int s = bz % 3, bi = bz / 3;
  int b = b0 + bi;
  if (nfs[b*4 + by] == 0 || nos[b*4 + bx] == 0) return;
  int m0 = by * 128, n0 = bx * 128;
  const __bf16* A = P + ((size_t)s * cs + bi) * kL * kD;
  const __bf16* B = xb + (size_t)b * kL * kD;
  __bf16* O = S + ((size_t)s * cs + bi) * kL * kL;
  __shared__ __bf16 smem[3*8192];
  f32x4 acc[4][4] = {};
  gemm_core_p3(A, B, m0, n0, acc, smem);
  const int lane = threadIdx.x & 63, wid = threadIdx.x >> 6;
  const int wm = (wid >> 1) * 64, wn = (wid & 1) * 64;
  const int row_l = wm + (lane & 15), col_l = wn + ((lane >> 4) << 2);
#pragma unroll
  for (int n = 0; n < 4; n++)
#pragma unroll
    for (int m = 0; m < 4; m++){
      int row = m0 + row_l + m*16;
      int colb = n0 + col_l + n*16;
      bf16x4 o;
#pragma unroll
      for (int r = 0; r < 4; r++) o[r] = (__bf16)(acc[n][m][r] * SCALE);
      *reinterpret_cast<bf16x4*>(O + (size_t)row * kL + colb) = o;
    }
}

// ---------------- wave-per-row masked softmax + gate combine (bf16 scores) ----------------
__global__ __launch_bounds__(256) void softmax_combine(
    const __bf16* __restrict__ S, const float* __restrict__ gate,
    const unsigned char* __restrict__ om, const int* __restrict__ n_om,
    const int* __restrict__ nfs,
    const float* __restrict__ tokc, const float* __restrict__ scon_s,
    float* __restrict__ c_sup, float* __restrict__ c_rep, int b0, int cs)
{
  int bi = blockIdx.y, b = b0 + bi;
  if (n_om[b] == 0) return;
  int i_base = blockIdx.x * 32;
  if (nfs[b*4 + (i_base >> 7)] == 0) return;
  int t = threadIdx.x, w = t >> 6, lane = t & 63;
  int c0 = lane * 8;
  const __bf16* ssup = S + ((size_t)0 * cs + bi) * (size_t)kL * kL;
  const __bf16* scon = S + ((size_t)1 * cs + bi) * (size_t)kL * kL;
  const __bf16* srep = S + ((size_t)2 * cs + bi) * (size_t)kL * kL;
  unsigned long long omv = *reinterpret_cast<const unsigned long long*>(om + (size_t)b*kL + c0);
  float csup_c[8], crep_c[8], ccon_c[8];
  bool msk[8];
#pragma unroll
  for (int u = 0; u < 8; u++){
    msk[u] = ((omv >> (8*u)) & 1ull) != 0;
    csup_c[u] = SCALE * tokc[0*kNT + b*kL + c0 + u];
    crep_c[u] = SCALE * tokc[1*kNT + b*kL + c0 + u];
    ccon_c[u] = SCALE * tokc[2*kNT + b*kL + c0 + u];
  }
  float sconst = SCALE * scon_s[0];
  float accS[8] = {}, accR[8] = {};
  int i0w = i_base + w * 8;
  for (int ii = 0; ii < 8; ii++){
    int i = i0w + ii;
    float g = gate[(size_t)b*kL + i];
    if (!(g > 0.f)) continue;
    float rcon_i = SCALE * tokc[3*kNT + b*kL + i] + sconst;
    size_t base = (size_t)i * kL + c0;
    bf16x8 sb = *reinterpret_cast<const bf16x8*>(ssup + base);
    bf16x8 cb = *reinterpret_cast<const bf16x8*>(scon + base);
    bf16x8 rb = *reinterpret_cast<const bf16x8*>(srep + base);
    float vs[8], vr[8];
#pragma unroll
    for (int u = 0; u < 8; u++){
      float sv = (float)sb[u], cv = (float)cb[u], rv = (float)rb[u];
      vs[u] = msk[u] ? (sv + csup_c[u]) : NEGF;
      vr[u] = msk[u] ? (rv + crep_c[u] + fast_tanh(cv + ccon_c[u] + rcon_i)) : NEGF;
    }
    float ms = vs[0], mr = vr[0];
#pragma unroll
    for (int u = 1; u < 8; u++){ ms = fmaxf(ms, vs[u]); mr = fmaxf(mr, vr[u]); }
    ms = wave_max(ms); mr = wave_max(mr);
    float es[8], er[8], zs = 0.f, zr = 0.f;
#pragma unroll
    for (int u = 0; u < 8; u++){
      es[u] = __expf(vs[u] - ms); er[u] = __expf(vr[u] - mr);
      zs += es[u]; zr += er[u];
    }
    zs = wave_sum(zs); zr = wave_sum(zr);
    float gs = g / zs, gr = g / zr;
#pragma unroll
    for (int u = 0; u < 8; u++){ accS[u] += gs * es[u]; accR[u] += gr * er[u]; }
  }
  __shared__ float lsS[4][kL];
  __shared__ float lsR[4][kL];
#pragma unroll
  for (int u = 0; u < 8; u++){ lsS[w][c0+u] = accS[u]; lsR[w][c0+u] = accR[u]; }
  __syncthreads();
  int col0 = t, col1 = t + 256;
  float vS0 = lsS[0][col0]+lsS[1][col0]+lsS[2][col0]+lsS[3][col0];
  float vR0 = lsR[0][col0]+lsR[1][col0]+lsR[2][col0]+lsR[3][col0];
  float vS1 = lsS[0][col1]+lsS[1][col1]+lsS[2][col1]+lsS[3][col1];
  float vR1 = lsR[0][col1]+lsR[1][col1]+lsR[2][col1]+lsR[3][col1];
  atomicAdd(&c_sup[(size_t)b*kL + col0], vS0);
  atomicAdd(&c_rep[(size_t)b*kL + col0], vR0);
  atomicAdd(&c_sup[(size_t)b*kL + col1], vS1);
  atomicAdd(&c_rep[(size_t)b*kL + col1], vR1);
}

// ---------------- weighted sums over xb -> insG2[lz][b][3*kD] (no atomics) ----------------
__global__ __launch_bounds__(256) void vec_kernel(
    const __bf16* __restrict__ xb, const float* __restrict__ gate,
    const float* __restrict__ c_sup, const float* __restrict__ c_rep,
    float* __restrict__ insG2)
{
  int b = blockIdx.y, dq = blockIdx.x, lz = blockIdx.z;
  int tid = threadIdx.x;
  __shared__ float g_s[256], cs_s[256], cr_s[256];
  __shared__ float acc_s[3][256];
  {
    int l = lz*256 + tid;
    g_s[tid]  = gate[b*kL + l];
    cs_s[tid] = c_sup[b*kL + l];
    cr_s[tid] = c_rep[b*kL + l];
  }
  for (int j = tid; j < 768; j += 256) (&acc_s[0][0])[j] = 0.f;
  __syncthreads();
  int dg = tid & 31;
  int ls = tid >> 5;
  int d0 = dq*256 + dg*8;
  float a[8] = {}, r[8] = {}, s[8] = {};
  const __bf16* xp = xb + (size_t)b * kL * kD + (size_t)(lz*256) * kD + d0;
#pragma unroll 4
  for (int i = 0; i < 32; i++){
    int l = ls + i*8;
    bf16x8 v = *reinterpret_cast<const bf16x8*>(xp + (size_t)l * kD);
    float g = g_s[l], cr = cr_s[l], csv = cs_s[l];
#pragma unroll
    for (int u = 0; u < 8; u++){
      float xv = (float)v[u];
      a[u] = fmaf(g,   xv, a[u]);
      r[u] = fmaf(cr,  xv, r[u]);
      s[u] = fmaf(csv, xv, s[u]);
    }
  }
#pragma unroll
  for (int u = 0; u < 8; u++){
    atomicAdd(&acc_s[0][dg*8+u], a[u]);
    atomicAdd(&acc_s[1][dg*8+u], r[u]);
    atomicAdd(&acc_s[2][dg*8+u], s[u]);
  }
  __syncthreads();
  int d = dq*256 + tid;
  size_t base = ((size_t)(lz*kB + b)) * (size_t)(3*kD);
  insG2[base + 0*kD + d] = acc_s[0][tid];
  insG2[base + 1*kD + d] = acc_s[1][tid];
  insG2[base + 2*kD + d] = acc_s[2][tid];
}

// ---------------- FFN1: hpart[y][b][kD] (no atomics) ----------------
__global__ __launch_bounds__(256) void ffn1_kernel(
    const float* __restrict__ insG2, const float* __restrict__ w_f1, float* __restrict__ hpart)
{
  int bx = blockIdx.x, by = blockIdx.y;
  int tid = threadIdx.x, lane = tid & 63, bg = tid >> 6;
  int k0 = by * 64;
  __shared__ float ins_s[64][32];
  {
    int b = tid >> 3, kk = (tid & 7) * 8;
    const float* p0 = insG2 + (size_t)b        * (size_t)(3*kD) + k0 + kk;
    const float* p1 = insG2 + (size_t)(kB + b) * (size_t)(3*kD) + k0 + kk;
    f32x4 v0a = *reinterpret_cast<const f32x4*>(p0);
    f32x4 v0b = *reinterpret_cast<const f32x4*>(p0 + 4);
    f32x4 v1a = *reinterpret_cast<const f32x4*>(p1);
    f32x4 v1b = *reinterpret_cast<const f32x4*>(p1 + 4);
#pragma unroll
    for (int i = 0; i < 4; i++){
      ins_s[kk+i][b]   = v0a[i] + v1a[i];
      ins_s[kk+4+i][b] = v0b[i] + v1b[i];
    }
  }
  __syncthreads();
  int c0 = bx*256 + lane*4;
  float acc[4][8] = {};
  const float* wp = w_f1 + (size_t)k0 * kD + c0;
#pragma unroll 4
  for (int k = 0; k < 64; k++){
    f32x4 w = *reinterpret_cast<const f32x4*>(wp + (size_t)k * kD);
    f32x4 i0 = *reinterpret_cast<const f32x4*>(&ins_s[k][bg*8]);
    f32x4 i1 = *reinterpret_cast<const f32x4*>(&ins_s[k][bg*8+4]);
#pragma unroll
    for (int c = 0; c < 4; c++){
#pragma unroll
      for (int j = 0; j < 4; j++){
        acc[c][j]   = fmaf(w[c], i0[j], acc[c][j]);
        acc[c][4+j] = fmaf(w[c], i1[j], acc[c][4+j]);
      }
    }
  }
  float* hp = hpart + (size_t)by * kB * kD + bx*256;
#pragma unroll
  for (int j = 0; j < 8; j++){
    f32x4 o;
#pragma unroll
    for (int c = 0; c < 4; c++) o[c] = acc[c][j];
    *reinterpret_cast<f32x4*>(hp + (size_t)(bg*8 + j) * kD + lane*4) = o;
  }
}

// ---------------- hreduce: hT2[b][kD] = relu(sum_y hpart + b_f1) ----------------
__global__ __launch_bounds__(256) void hreduce_kernel(
    const float* __restrict__ hpart, const float* __restrict__ b_f1, float* __restrict__ hT2)
{
  int idx = blockIdx.x * 256 + threadIdx.x;
  size_t off = (size_t)idx * 4;
  f32x4 s = {};
  for (int y = 0; y < 48; y++)
    s += *reinterpret_cast<const f32x4*>(hpart + (size_t)y * kB * kD + off);
  int k = (int)(off & (kD - 1));
  f32x4 bv = *reinterpret_cast<const f32x4*>(b_f1 + k);
  f32x4 o;
#pragma unroll
  for (int i = 0; i < 4; i++) o[i] = fmaxf(s[i] + bv[i], 0.f);
  *reinterpret_cast<f32x4*>(hT2 + off) = o;
}

// ---------------- FFN2: f2part[y][b][kD] (no atomics) ----------------
__global__ __launch_bounds__(256) void ffn2_kernel(
    const float* __restrict__ hT2, const float* __restrict__ w_f2, float* __restrict__ f2part)
{
  int bx = blockIdx.x, by = blockIdx.y;
  int tid = threadIdx.x, lane = tid & 63, bg = tid >> 6;
  int k0 = by * 64;
  __shared__ float hs[64][32];
  {
    int b = tid >> 3, kk = (tid & 7) * 8;
    const float* p = hT2 + (size_t)b * kD + k0 + kk;
    f32x4 va = *reinterpret_cast<const f32x4*>(p);
    f32x4 vb = *reinterpret_cast<const f32x4*>(p + 4);
#pragma unroll
    for (int i = 0; i < 4; i++){ hs[kk+i][b] = va[i]; hs[kk+4+i][b] = vb[i]; }
  }
  __syncthreads();
  int c0 = bx*256 + lane*4;
  float acc[4][8] = {};
  const float* wp = w_f2 + (size_t)k0 * kD + c0;
#pragma unroll 4
  for (int k = 0; k < 64; k++){
    f32x4 w = *reinterpret_cast<const f32x4*>(wp + (size_t)k * kD);
    f32x4 i0 = *reinterpret_cast<const f32x4*>(&hs[k][bg*8]);
    f32x4 i1 = *reinterpret_cast<const f32x4*>(&hs[k][bg*8+4]);
#pragma unroll
    for (int c = 0; c < 4; c++){
#pragma unroll
      for (int j = 0; j < 4; j++){
        acc[c][j]   = fmaf(w[c], i0[j], acc[c][j]);
        acc[c][4+j] = fmaf(w[c], i1[j], acc[c][4+j]);
      }
    }
  }
  float* fp = f2part + (size_t)by * kB * kD + bx*256;
#pragma unroll
  for (int j = 0; j < 8; j++){
    f32x4 o;
#pragma unroll
    for (int c = 0; c < 4; c++) o[c] = acc[c][j];
    *reinterpret_cast<f32x4*>(fp + (size_t)(bg*8 + j) * kD + lane*4) = o;
  }
}

// ---------------- LayerNorm (reduces 16 f2 partials, adds b_f2) ----------------
__global__ __launch_bounds__(256) void ln_kernel(
    const float* __restrict__ f2part, const float* __restrict__ b_f2,
    const float* __restrict__ g, const float* __restrict__ bta, float* __restrict__ out)
{
  int b = blockIdx.x, t = threadIdx.x;
  __shared__ float red[4];
  float v[4]; float s1 = 0.f, s2 = 0.f;
#pragma unroll
  for (int u = 0; u < 4; u++){
    int o = t + u*256;
    float acc = b_f2[o];
    for (int y = 0; y < 16; y++)
      acc += f2part[(size_t)y * kB * kD + (size_t)b * kD + o];
    v[u] = acc;
    s1 += v[u]; s2 += v[u]*v[u];
  }
  s1 = blk_sum<4>(s1, red);
  s2 = blk_sum<4>(s2, red);
  float mu = s1 * (1.f/(float)kD);
  float var = s2 * (1.f/(float)kD) - mu*mu;
  float inv = rsqrtf(var + 1e-5f);
#pragma unroll
  for (int u = 0; u < 4; u++){
    int o = t + u*256;
    out[(size_t)b*kD + o] = (v[u] - mu) * inv * g[o] + bta[o];
  }
}

// ---------------- host launch ----------------
extern "C" void kernel_launch(void* const* d_in, const int* in_sizes, int n_in,
                              void* d_out, int out_size, void* d_ws, size_t ws_size,
                              hipStream_t stream)
{
  const float* x      = (const float*)d_in[0];
  const int*   ids    = (const int*)d_in[1];
  const int*   pad_p  = (const int*)d_in[2];
  const int*   sep_p  = (const int*)d_in[3];
  const float* w_anom = (const float*)d_in[4];
  const float* b_anom = (const float*)d_in[5];
  const float* w_sq = (const float*)d_in[6];  const float* b_sq = (const float*)d_in[7];
  const float* w_sk = (const float*)d_in[8];  const float* b_sk = (const float*)d_in[9];
  const float* w_cq = (const float*)d_in[10]; const float* b_cq = (const float*)d_in[11];
  const float* w_ck = (const float*)d_in[12]; const float* b_ck = (const float*)d_in[13];
  const float* w_rq = (const float*)d_in[14]; const float* b_rq = (const float*)d_in[15];
  const float* w_rk = (const float*)d_in[16]; const float* b_rk = (const float*)d_in[17];
  const float* w_f1 = (const float*)d_in[18]; const float* b_f1 = (const float*)d_in[19];
  const float* w_f2 = (const float*)d_in[20]; const float* b_f2 = (const float*)d_in[21];
  const float* lng  = (const float*)d_in[22]; const float* lnb  = (const float*)d_in[23];
  float* out = (float*)d_out;

  char* p = (char*)d_ws;
  auto carve = [&](size_t bytes) -> void* {
    void* r = (void*)p; p += (bytes + 255) & ~(size_t)255; return r;
  };
  int* n_fm = (int*)carve(kB*4);
  int* n_om = (int*)carve(kB*4);
  int* nfs  = (int*)carve(kB*4*4);
  int* nos  = (int*)carve(kB*4*4);
  unsigned char* fm = (unsigned char*)carve(kB*kL);
  unsigned char* om = (unsigned char*)carve(kB*kL);
  float* logits = (float*)carve((size_t)kNT*4);
  float* gate   = (float*)carve((size_t)kNT*4);
  float* c_sup  = (float*)carve((size_t)kNT*4);
  float* c_rep  = (float*)carve((size_t)kNT*4);
  float* tokc   = (float*)carve((size_t)4*kNT*4);
  float* vecs4  = (float*)carve((size_t)4*kD*4);
  float* scon_s = (float*)carve(256);
  float* insG2  = (float*)carve((size_t)2*kB*3*kD*4);
  float* hpart  = (float*)carve((size_t)48*kB*kD*4);
  float* hT2    = (float*)carve((size_t)kB*kD*4);
  float* f2part = (float*)carve((size_t)16*kB*kD*4);
  __bf16* Bmat = (__bf16*)carve((size_t)3*kD*kD*2);
  __bf16* xb   = (__bf16*)carve((size_t)kNT*kD*2);

  size_t used = (size_t)(p - (char*)d_ws);
  size_t wb_bytes = (size_t)6*kD*kD*2;
  size_t per_chunk = (size_t)3*kL*kD*2 + (size_t)3*kL*kL*2;
  long avail = (long)ws_size - (long)used - 8192;
  __bf16 *Wb, *P, *scores;
  int chunkB;
  if (avail >= (long)wb_bytes && avail >= (long)per_chunk){
    chunkB = (int)(avail / (long)per_chunk);
    if (chunkB > kB) chunkB = kB;
    if ((size_t)chunkB * per_chunk < wb_bytes){
      Wb = (__bf16*)carve(wb_bytes);
      used = (size_t)(p - (char*)d_ws);
      avail = (long)ws_size - (long)used - 8192;
      chunkB = (avail > 0) ? (int)(avail / (long)per_chunk) : 1;
      if (chunkB < 1) chunkB = 1;
      if (chunkB > kB) chunkB = kB;
      P = (__bf16*)p;
    } else {
      Wb = (__bf16*)p; P = (__bf16*)p;
    }
  } else {
    Wb = (__bf16*)carve(wb_bytes);
    used = (size_t)(p - (char*)d_ws);
    avail = (long)ws_size - (long)used - 8192;
    chunkB = (avail > 0) ? (int)(avail / (long)per_chunk) : 1;
    if (chunkB < 1) chunkB = 1;
    if (chunkB > kB) chunkB = kB;
    P = (__bf16*)p;
  }
  scores = P + (size_t)3*chunkB*kL*kD;

  masks_kernel<<<kB, 256, 0, stream>>>(ids, pad_p, sep_p, n_fm, n_om, nfs, nos, fm, om, c_sup, c_rep);
  conv_w_kernel<<<dim3(kD*kD/2048, 6), 256, 0, stream>>>(w_sq, w_sk, w_cq, w_ck, w_rq, w_rk, Wb);
  wb_vec_kernel<<<dim3(kD/4, 5), 256, 0, stream>>>(w_sk, b_sq, w_rk, b_rq, w_ck, b_cq, w_cq, b_ck, vecs4, scon_s);
  prep_x_kernel<<<kNT/2, 256, 0, stream>>>(x, w_anom, b_anom, vecs4, xb, logits, tokc);
  gate_kernel<<<kB, 256, 0, stream>>>(logits, fm, n_fm, gate);
  combine_gemm<<<dim3(8, 8, 3), 256, 0, stream>>>(Wb, Bmat);

  for (int b0 = 0; b0 < kB; b0 += chunkB){
    int cs = chunkB; if (b0 + cs > kB) cs = kB - b0;
    proj_gemm<<<dim3(8, cs*4, 3), 256, 0, stream>>>(xb, Bmat, nfs, P, b0, cs);
    score_gemm<<<dim3(4, 4, cs*3), 256, 0, stream>>>(P, xb, nfs, nos, scores, b0, cs);
    softmax_combine<<<dim3(kL/32, cs), 256, 0, stream>>>(scores, gate, om, n_om, nfs,
        tokc, scon_s, c_sup, c_rep, b0, cs);
  }

  vec_kernel<<<dim3(4, kB, 2), 256, 0, stream>>>(xb, gate, c_sup, c_rep, insG2);
  ffn1_kernel<<<dim3(4, 48), 256, 0, stream>>>(insG2, w_f1, hpart);
  hreduce_kernel<<<32, 256, 0, stream>>>(hpart, b_f1, hT2);
  ffn2_kernel<<<dim3(4, 16), 256, 0, stream>>>(hT2, w_f2, f2part);
  ln_kernel<<<kB, 256, 0, stream>>>(f2part, b_f2, lng, lnb, out);
}